// Round 8
// baseline (340.681 us; speedup 1.0000x reference)
//
#include <hip/hip_runtime.h>
#include <math.h>

// Exact-order float32 arithmetic: numpy/jax evaluate left-to-right with no
// FMA contraction. hipcc defaults to -ffp-contract=fast, which would change
// rounding -> possible spike-time shift -> large voltage absmax error.
#pragma clang fp contract(off)

// R8: all-VALU spike resolution via DPP quad broadcasts (no ballot in loop).
// Neuron->lane map chosen so the in-step dependency chain stays in quad 0:
//   lane 0: LLBN   (no in-step dependence; I fully set by prev-step bits)
//   lane 1: EBN    <- z2 (lane0)   : quad_perm broadcast lane0
//   lane 2: TN     <- z3 (lane1)   : quad_perm broadcast lane1
//   lane 3: MN     <- z5 (lane2)   : quad_perm broadcast lane2
//   lane 4: IFN    <- z3 (lane1)   : ds_swizzle (off critical path: IFN's
//                                    fire feeds only the NEXT step's LLBN)
// Each lane computes BOTH variant tails v1_0/v1_1; resolution = DPP bcast of
// the controller's actual v1 + v_cmp against a per-lane threshold (30 for
// the controlled lane, +INF for the rest) + v_cndmask. Everything stays in
// the vector pipe -> no VALU<->SALU round trips per step.
// Cycle detection (once per 8 steps, ballots OK there): state =
// (v,u,zf) x 5 lanes; bitwise equality with an anchor => the remaining
// output repeats the window [anchor, t). Fine anchors every 40 steps
// (period 40 observed) + power-of-2 Brent anchors as generic fallback.

template <int CTRL>
__device__ __forceinline__ float qb(float x) {
    // v_mov_b32_dpp quad_perm broadcast; bound_ctrl=1 (invalid lanes -> 0,
    // harmless: their compare threshold is +INF)
    return __int_as_float(__builtin_amdgcn_update_dpp(
        0, __float_as_int(x), CTRL, 0xF, 0xF, true));
}

template <int OFS>
__device__ __forceinline__ float swz(float x) {
    // ds_swizzle BitMode broadcast: lane reads lane ((i&and)|or)^xor
    return __int_as_float(__builtin_amdgcn_ds_swizzle(__float_as_int(x), OFS));
}

__global__ __launch_bounds__(256) void net_sim(const float* __restrict__ mat,
                                               const float* __restrict__ w,
                                               float* __restrict__ out,
                                               int* __restrict__ ws,
                                               int T) {
    __shared__ double red[256];
    const int tid = threadIdx.x;

    // ---- z_plus = sum(input_mat * w0), f32 products accumulated in f64 ----
    const float w0 = w[0];
    double s = 0.0;
    for (int i = tid; i < 127 * 127; i += 256) {
        float p = mat[i] * w0;   // elementwise product rounded to f32 (as ref)
        s += (double)p;
    }
    red[tid] = s;
    __syncthreads();
    #pragma unroll
    for (int off = 128; off > 0; off >>= 1) {
        if (tid < off) red[tid] += red[tid + off];
        __syncthreads();
    }
    if (tid >= 5) return;   // 5 lanes of wave 0 continue; no more barriers

    const float z_plus = (float)red[0];

    const float w2 = w[2], w3 = w[3], w5 = w[5], w6 = w[6], w7 = w[7],
                w8 = w[8], w9 = w[9], w10 = w[10], w11 = w[11];
    const float zp_w1 = z_plus * w[1];
    const float zp_w4 = z_plus * w[4];

    // Validated constant-I set (R2..R7, absmax 0.0). z*w is exactly +0.0f
    // or w; x + (+0.0f) == x for the values involved.
    const float I2_00 = w2 * (zp_w1 - 0.0f) + w3 * 0.0f;
    const float I2_10 = w2 * (zp_w1 - 0.0f) + w3 * 1.0f;
    const float I2_01 = w2 * (zp_w1 - w7)   + w3 * 0.0f;
    const float I2_11 = w2 * (zp_w1 - w7)   + w3 * 1.0f;
    const float I3_0  = zp_w4 + 0.0f * w5;
    const float I3_1  = zp_w4 + 1.0f * w5;
    const float I4_0  = 0.0f * w6;
    const float I4_1  = 1.0f * w6;
    const float I5_00 = w9 * (0.0f * w8) + w10 * 0.0f;   // (z3, z5p)
    const float I5_10 = w9 * (1.0f * w8) + w10 * 0.0f;
    const float I5_01 = w9 * (0.0f * w8) + w10 * 1.0f;
    const float I5_11 = w9 * (1.0f * w8) + w10 * 1.0f;
    const float I6_0  = 0.0f * w11;
    const float I6_1  = 1.0f * w11;

    const int lane = tid;  // 0..4; neuron = {0:LLBN,1:EBN,2:TN,3:MN,4:IFN}
    // per-lane params; ka = float(TAU*DT*a) computed in f64 like Python
    const float ka = lane == 0 ? (float)(0.25 * 0.1) : (float)(0.25 * 0.02);
    const float b  = lane == 0 ? -0.075f : (lane == 2 ? 0.2f : 0.25f);
    const float cc = lane <= 1 ? -55.0f : -65.0f;
    const float d  = lane == 1 ? 0.05f : 6.0f;
    float v = lane == 0 ? -60.0f : (lane == 2 ? -70.0f : -64.0f);
    float u = lane == 0 ? 4.5f   : (lane == 2 ? -14.0f : -16.0f);

    // per-lane variant-I constants (a: z5p=0, b: z5p=1; equal off-TN).
    const float K0a = lane == 1 ? I3_0 : lane == 2 ? I5_00
                    : lane == 3 ? I6_0 : lane == 4 ? I4_0 : 0.0f;
    const float K0b = lane == 2 ? I5_01 : K0a;
    const float K1a = lane == 1 ? I3_1 : lane == 2 ? I5_10
                    : lane == 3 ? I6_1 : lane == 4 ? I4_1 : 0.0f;
    const float K1b = lane == 2 ? I5_11 : K1a;
    const bool is_l0 = (lane == 0);

    const float INF = __builtin_huge_valf();
    const float thrA = lane == 1 ? 30.0f : INF;   // round A resolves EBN
    const float thrB = lane == 2 ? 30.0f : INF;   // round B resolves TN
    const float thrC = lane == 3 ? 30.0f : INF;   // round C resolves MN
    const float thrI = lane == 4 ? 30.0f : INF;   // swizzle resolves IFN

    // output row per lane: rows are [LLBN,EBN,IFN,TN,MN] = [0,1,4,2,3]-lanes
    const int row = lane == 2 ? 3 : lane == 3 ? 4 : lane == 4 ? 2 : lane;
    float* __restrict__ psp = out + row * T;           // spikes row
    float* __restrict__ pvv = out + 5 * T + row * T;   // volts row

    float zf = 0.0f;     // this lane's previous-step spike (0/1)
    float z4v = 0.0f;    // broadcast of IFN's previous-step spike

    // ---- cycle-detection anchors: fine (cadence 40) + Brent fallback ----
    float fav = 0.0f, fau = 0.0f, faz = 0.0f; int fa_t = -1;
    float cav = 0.0f, cau = 0.0f, caz = 0.0f; int ca_t = -1;
    int next_coarse = 8;
    int t_det = -1, Pf = 0;

    float zb[8], vb[8];

    int t = 0;
    for (; t + 8 <= T; t += 8) {
        // ---- block top: compare against anchors FIRST, then refresh ----
        int hitA = -1;
        if (fa_t >= 0) {
            unsigned long long mv =
                __ballot(__float_as_uint(v) == __float_as_uint(fav));
            unsigned long long mu =
                __ballot(__float_as_uint(u) == __float_as_uint(fau));
            unsigned long long mz =
                __ballot(__float_as_uint(zf) == __float_as_uint(faz));
            if (((mv & mu & mz) & 0x1Full) == 0x1Full) hitA = fa_t;
        }
        if (hitA < 0 && ca_t >= 0) {
            unsigned long long mv =
                __ballot(__float_as_uint(v) == __float_as_uint(cav));
            unsigned long long mu =
                __ballot(__float_as_uint(u) == __float_as_uint(cau));
            unsigned long long mz =
                __ballot(__float_as_uint(zf) == __float_as_uint(caz));
            if (((mv & mu & mz) & 0x1Full) == 0x1Full) hitA = ca_t;
        }
        if (hitA >= 0) { t_det = t; Pf = t - hitA; break; }
        if (t && (t % 40) == 0) { fav = v; fau = u; faz = zf; fa_t = t; }
        if (t == next_coarse) {
            cav = v; cau = u; caz = zf; ca_t = t; next_coarse <<= 1;
        }

        #pragma unroll
        for (int j = 0; j < 8; ++j) {
            // ---- J prep from prev-step bits (off critical path) ----
            bool cown = (zf >= 0.5f);           // lane-local prev spike
            float J0 = cown ? K0b : K0a;        // TN: z5p select; others equal
            float J1 = cown ? K1b : K1a;
            float s1 = cown ? I2_10 : I2_00;    // lane0: cown == z2p
            float s2 = cown ? I2_11 : I2_01;
            float fI2 = (z4v >= 0.5f) ? s2 : s1;
            J0 = is_l0 ? fI2 : J0;
            J1 = is_l0 ? fI2 : J1;

            // ---- common izh head (I-independent) ----
            float t1 = 0.04f * v;
            float t2 = t1 * v;
            float t3 = 5.0f * v;
            float t4 = t2 + t3;
            float t5 = t4 + 140.0f;
            float t6 = t5 - u;
            float bv = b * v;
            float bvu = bv - u;
            float du = ka * bvu;
            float u1 = u + du;
            float u1d = u1 + d;

            // ---- both variant tails (parallel) ----
            float t7_0 = t6 + J0;
            float dv_0 = 0.25f * t7_0;   // TAU*DT = 0.25 exactly
            float v1_0 = v + dv_0;
            float t7_1 = t6 + J1;
            float dv_1 = 0.25f * t7_1;
            float v1_1 = v + dv_1;

            // ---- resolution rounds, all in the vector pipe ----
            float cA = qb<0x00>(v1_0);              // lane0's actual v1
            float x01 = (cA >= thrA) ? v1_1 : v1_0; // EBN resolved
            float sF = swz<0x20>(x01);              // EBN actual -> IFN (slack)
            float cB = qb<0x55>(x01);               // EBN's actual v1
            float x02 = (cB >= thrB) ? v1_1 : x01;  // TN resolved
            float cC = qb<0xAA>(x02);               // TN's actual v1
            float x03 = (cC >= thrC) ? v1_1 : x02;  // MN resolved
            float v1a = (sF >= thrI) ? v1_1 : x03;  // IFN resolved

            // ---- fire/reset (local) ----
            bool fire = (v1a >= 30.0f);
            v = fire ? cc : v1a;
            u = fire ? u1d : u1;     // z*d is exactly d or +0.0f
            zf = fire ? 1.0f : 0.0f;
            z4v = swz<0x80>(zf);     // IFN spike -> next step's LLBN (slack)

            zb[j] = zf;
            vb[j] = v;
        }
        // batched flush (rows 16B-aligned at t; t % 8 == 0)
        *(float4*)(psp)     = make_float4(zb[0], zb[1], zb[2], zb[3]);
        *(float4*)(psp + 4) = make_float4(zb[4], zb[5], zb[6], zb[7]);
        *(float4*)(pvv)     = make_float4(vb[0], vb[1], vb[2], vb[3]);
        *(float4*)(pvv + 4) = make_float4(vb[4], vb[5], vb[6], vb[7]);
        psp += 8;
        pvv += 8;
    }
    // tail (T not divisible by 8), only when no cycle was detected
    for (; t < T && t_det < 0; ++t) {
        bool cown = (zf >= 0.5f);
        float J0 = cown ? K0b : K0a;
        float J1 = cown ? K1b : K1a;
        float s1 = cown ? I2_10 : I2_00;
        float s2 = cown ? I2_11 : I2_01;
        float fI2 = (z4v >= 0.5f) ? s2 : s1;
        J0 = is_l0 ? fI2 : J0;
        J1 = is_l0 ? fI2 : J1;
        float t1 = 0.04f * v;
        float t2 = t1 * v;
        float t3 = 5.0f * v;
        float t4 = t2 + t3;
        float t5 = t4 + 140.0f;
        float t6 = t5 - u;
        float bv = b * v;
        float bvu = bv - u;
        float du = ka * bvu;
        float u1 = u + du;
        float u1d = u1 + d;
        float t7_0 = t6 + J0;
        float dv_0 = 0.25f * t7_0;
        float v1_0 = v + dv_0;
        float t7_1 = t6 + J1;
        float dv_1 = 0.25f * t7_1;
        float v1_1 = v + dv_1;
        float cA = qb<0x00>(v1_0);
        float x01 = (cA >= thrA) ? v1_1 : v1_0;
        float sF = swz<0x20>(x01);
        float cB = qb<0x55>(x01);
        float x02 = (cB >= thrB) ? v1_1 : x01;
        float cC = qb<0xAA>(x02);
        float x03 = (cC >= thrC) ? v1_1 : x02;
        float v1a = (sF >= thrI) ? v1_1 : x03;
        bool fire = (v1a >= 30.0f);
        v = fire ? cc : v1a;
        u = fire ? u1d : u1;
        zf = fire ? 1.0f : 0.0f;
        z4v = swz<0x80>(zf);
        psp[0] = zf;
        pvv[0] = v;
        ++psp; ++pvv;
    }

    // publish detection result (ws is re-poisoned before every call)
    if (lane == 0) {
        ws[0] = (t_det >= 0) ? 1 : 0;
        ws[1] = t_det;
        ws[2] = Pf;
    }
}

// Fills out[r, t] for t in [t_det, T) with the periodic continuation
// out[r, t_det - P + ((t - t_det) mod P)]. No-op when no cycle was found.
__global__ __launch_bounds__(256) void fill_cycle(float* __restrict__ out,
                                                  const int* __restrict__ ws,
                                                  int T) {
    if (ws[0] == 0) return;
    const int t0 = ws[1];
    const int P  = ws[2];
    const int r  = blockIdx.y;                    // 0..9 (row)
    const float* __restrict__ src = out + (size_t)r * T + (t0 - P);
    float* __restrict__ dst       = out + (size_t)r * T + t0;
    const int n = T - t0;
    for (int i = blockIdx.x * blockDim.x + threadIdx.x; i < n;
         i += gridDim.x * blockDim.x) {
        dst[i] = src[i % P];
    }
}

extern "C" void kernel_launch(void* const* d_in, const int* in_sizes, int n_in,
                              void* d_out, int out_size, void* d_ws, size_t ws_size,
                              hipStream_t stream) {
    const float* mat = (const float*)d_in[0];
    const float* w   = (const float*)d_in[1];
    // out_size = 2 outputs * 5 neurons * T  -> T = out_size/10
    int T = out_size / 10;
    net_sim<<<1, 256, 0, stream>>>(mat, w, (float*)d_out, (int*)d_ws, T);
    dim3 grid(40, 10, 1);
    fill_cycle<<<grid, 256, 0, stream>>>((float*)d_out, (const int*)d_ws, T);
}

// Round 9
// 305.193 us; speedup vs baseline: 1.1163x; 1.1163x over previous
//
#include <hip/hip_runtime.h>

// Exact-order float32 arithmetic: numpy/jax evaluate left-to-right with no
// FMA contraction. hipcc defaults to -ffp-contract=fast, which would change
// rounding -> possible spike-time shift -> large voltage absmax error.
#pragma clang fp contract(off)

// R9 = R5/R6 datapath (measured-best ~334 cyc/step, bit-exact absmax 0.0)
//      + rolling-40 fine anchor (P=40 measured stable in R6/R7/R8)
//      + SGPR-mask cndmask for the actual-I select (validated in R7)
// Lane map (wave 0):
//   0   : LLBN (no speculation: I2 depends only on prev-step bits)
//   1,2 : EBN  speculating z2 = 0,1
//   3,4 : IFN  speculating z3 = 0,1
//   5,6 : TN   speculating z3 = 0,1   (known z5p folded into candidates)
//   7,8 : MN   speculating z5 = 0,1
// Cycle detection: state = {v,u} x 9 lanes + carry bits. Bitwise equality
// with an anchor => outputs repeat the window [anchor, t). Rolling anchor
// of age exactly 40 checked at t%40==0; Brent pow-2 anchors as fallback
// (any period, checked at the other 8-step block tops).

__device__ __forceinline__ float sel_mask(float a, float b, unsigned long long m) {
    float r;
    // D = m.bit[lane] ? S1 : S0   (VOP3 v_cndmask with SGPR-pair condition)
    asm("v_cndmask_b32 %0, %1, %2, %3" : "=v"(r) : "v"(a), "v"(b), "s"(m));
    return r;
}

__global__ __launch_bounds__(256) void net_sim(const float* __restrict__ mat,
                                               const float* __restrict__ w,
                                               float* __restrict__ out,
                                               int* __restrict__ ws,
                                               int T) {
    __shared__ double red[256];
    const int tid = threadIdx.x;

    // ---- z_plus = sum(input_mat * w0), f32 products accumulated in f64 ----
    const float w0 = w[0];
    double s = 0.0;
    for (int i = tid; i < 127 * 127; i += 256) {
        float p = mat[i] * w0;   // elementwise product rounded to f32 (as ref)
        s += (double)p;
    }
    red[tid] = s;
    __syncthreads();
    #pragma unroll
    for (int off = 128; off > 0; off >>= 1) {
        if (tid < off) red[tid] += red[tid + off];
        __syncthreads();
    }
    if (tid >= 9) return;   // 9 lanes of wave 0 continue; no more barriers

    const float z_plus = (float)red[0];

    const float w2 = w[2], w3 = w[3], w5 = w[5], w6 = w[6], w7 = w[7],
                w8 = w[8], w9 = w[9], w10 = w[10], w11 = w[11];
    const float zp_w1 = z_plus * w[1];
    const float zp_w4 = z_plus * w[4];

    // Validated constant-I set (R2..R8, absmax 0.0). z*w is exactly +0.0f
    // or w; x + (+0.0f) == x for the values involved.
    const float I2_00 = w2 * (zp_w1 - 0.0f) + w3 * 0.0f;
    const float I2_10 = w2 * (zp_w1 - 0.0f) + w3 * 1.0f;
    const float I2_01 = w2 * (zp_w1 - w7)   + w3 * 0.0f;
    const float I2_11 = w2 * (zp_w1 - w7)   + w3 * 1.0f;
    const float I3_0  = zp_w4 + 0.0f * w5;
    const float I3_1  = zp_w4 + 1.0f * w5;
    const float I4_0  = 0.0f * w6;
    const float I4_1  = 1.0f * w6;
    const float I5_00 = w9 * (0.0f * w8) + w10 * 0.0f;   // (z3, z5p)
    const float I5_10 = w9 * (1.0f * w8) + w10 * 0.0f;
    const float I5_01 = w9 * (0.0f * w8) + w10 * 1.0f;
    const float I5_11 = w9 * (1.0f * w8) + w10 * 1.0f;
    const float I6_0  = 0.0f * w11;
    const float I6_1  = 1.0f * w11;

    const int lane = tid;  // 0..8
    const int g = lane == 0 ? 0 : lane <= 2 ? 1 : lane <= 4 ? 2 : lane <= 6 ? 3 : 4;

    // per-lane params; ka = float(TAU*DT*a) computed in f64 like Python
    const float ka = lane == 0 ? (float)(0.25 * 0.1) : (float)(0.25 * 0.02);
    const float b  = lane == 0 ? -0.075f : (g == 3 ? 0.2f : 0.25f);
    const float c  = g <= 1 ? -55.0f : -65.0f;
    const float d  = g == 1 ? 0.05f : 6.0f;
    float v = g == 0 ? -60.0f : (g == 3 ? -70.0f : -64.0f);
    float u = g == 0 ? 4.5f   : (g == 3 ? -14.0f : -16.0f);

    // candidate-I vectors: variant0/variant1 per group, for z5p=0(a)/1(b).
    const float C0a = g == 0 ? I2_00 : g == 1 ? I3_0 : g == 2 ? I4_0
                    : g == 3 ? I5_00 : I6_0;
    const float C0b = g == 0 ? I2_00 : g == 1 ? I3_0 : g == 2 ? I4_0
                    : g == 3 ? I5_01 : I6_0;
    const float C1a = g == 1 ? I3_1 : g == 2 ? I4_1 : g == 3 ? I5_10
                    : g == 4 ? I6_1 : 0.0f;
    const float C1b = g == 1 ? I3_1 : g == 2 ? I4_1 : g == 3 ? I5_11
                    : g == 4 ? I6_1 : 0.0f;

    const bool is_lane0  = (lane == 0);
    const bool spec_var1 = (lane == 2) | (lane == 4) | (lane == 6) | (lane == 8);

    float* __restrict__ psp = out + g * T;           // spikes row
    float* __restrict__ pvv = out + 5 * T + g * T;   // volts row

    int z2 = 0, z4 = 0, z5 = 0;   // prev-step bits (z2p, z4p, z5p) — uniform

    // ---- cycle-detection: rolling-40 anchor + Brent pow-2 fallback ----
    float rav = 0.0f, rau = 0.0f; int raz2 = 0, raz4 = 0, raz5 = 0, ra_t = -1;
    float cav = 0.0f, cau = 0.0f; int caz2 = 0, caz4 = 0, caz5 = 0, ca_t = -1;
    int next_coarse = 8;
    int t_det = -1, Pf = 0;

    float zb[8], vb[8];

    int t = 0;
    for (; t + 8 <= T; t += 8) {
        // ---- block top: anchor compares / refresh ----
        if (t % 40 == 0) {
            if (ra_t >= 0) {
                unsigned long long mv =
                    __ballot(__float_as_uint(v) == __float_as_uint(rav));
                unsigned long long mu =
                    __ballot(__float_as_uint(u) == __float_as_uint(rau));
                if (((mv & mu) & 0x1FFull) == 0x1FFull &&
                    z2 == raz2 && z4 == raz4 && z5 == raz5) {
                    t_det = t; Pf = t - ra_t;   // Pf == 40
                    break;
                }
            }
            if (t) { rav = v; rau = u; raz2 = z2; raz4 = z4; raz5 = z5; ra_t = t; }
        } else if (ca_t >= 0) {
            unsigned long long mv =
                __ballot(__float_as_uint(v) == __float_as_uint(cav));
            unsigned long long mu =
                __ballot(__float_as_uint(u) == __float_as_uint(cau));
            if (((mv & mu) & 0x1FFull) == 0x1FFull &&
                z2 == caz2 && z4 == caz4 && z5 == caz5) {
                t_det = t; Pf = t - ca_t;
                break;
            }
        }
        if (t == next_coarse) {
            cav = v; cau = u; caz2 = z2; caz4 = z4; caz5 = z5; ca_t = t;
            next_coarse <<= 1;
        }

        #pragma unroll
        for (int j = 0; j < 8; ++j) {
            // candidate-I prep from prev-step bits (off critical path)
            float fI2 = z4 ? (z2 ? I2_11 : I2_01) : (z2 ? I2_10 : I2_00);
            float V0 = z5 ? C0b : C0a;
            float V1 = z5 ? C1b : C1a;
            V0 = is_lane0 ? fI2 : V0;
            float Ib = spec_var1 ? V1 : V0;

            // common izh head (I-independent)
            float t1 = 0.04f * v;
            float t2 = t1 * v;
            float t3 = 5.0f * v;
            float t4 = t2 + t3;
            float t5 = t4 + 140.0f;
            float t6 = t5 - u;
            float bv = b * v;
            float bvu = bv - u;
            float du = ka * bvu;
            float u1 = u + du;

            // speculative (ballot) tail
            float t7b = t6 + Ib;
            float dvb = 0.25f * t7b;     // TAU*DT = 0.25 exactly
            float v1b = v + dvb;
            unsigned long long m = __ballot(v1b >= 30.0f);

            // scalar resolution (uniform)
            int nz2 = (int)(m & 1ull);
            int z3  = (int)((m >> (1 + nz2)) & 1ull);
            int nz4 = (int)((m >> (3 + z3)) & 1ull);
            int nz5 = (int)((m >> (5 + z3)) & 1ull);
            unsigned long long ssel =
                (nz2 ? 0x006ull : 0ull) | (z3 ? 0x078ull : 0ull)
              | (nz5 ? 0x180ull : 0ull);

            // actual tail, recomputed locally; I select via SGPR-pair mask
            float Ia = sel_mask(V0, V1, ssel);
            float t7a = t6 + Ia;
            float dva = 0.25f * t7a;
            float v1a = v + dva;
            bool fa = (v1a >= 30.0f);
            v = fa ? c : v1a;
            float u1d = u1 + d;
            u = fa ? u1d : u1;           // z*d is exactly d or +0.0f

            zb[j] = fa ? 1.0f : 0.0f;
            vb[j] = v;

            z2 = nz2; z4 = nz4; z5 = nz5;
        }
        // batched flush (rows 16B-aligned at t; t % 8 == 0)
        *(float4*)(psp)     = make_float4(zb[0], zb[1], zb[2], zb[3]);
        *(float4*)(psp + 4) = make_float4(zb[4], zb[5], zb[6], zb[7]);
        *(float4*)(pvv)     = make_float4(vb[0], vb[1], vb[2], vb[3]);
        *(float4*)(pvv + 4) = make_float4(vb[4], vb[5], vb[6], vb[7]);
        psp += 8;
        pvv += 8;
    }
    // tail (T not divisible by 8), only when no cycle was detected
    for (; t < T && t_det < 0; ++t) {
        float fI2 = z4 ? (z2 ? I2_11 : I2_01) : (z2 ? I2_10 : I2_00);
        float V0 = z5 ? C0b : C0a;
        float V1 = z5 ? C1b : C1a;
        V0 = is_lane0 ? fI2 : V0;
        float Ib = spec_var1 ? V1 : V0;
        float t1 = 0.04f * v;
        float t2 = t1 * v;
        float t3 = 5.0f * v;
        float t4 = t2 + t3;
        float t5 = t4 + 140.0f;
        float t6 = t5 - u;
        float bv = b * v;
        float bvu = bv - u;
        float du = ka * bvu;
        float u1 = u + du;
        float t7b = t6 + Ib;
        float dvb = 0.25f * t7b;
        float v1b = v + dvb;
        unsigned long long m = __ballot(v1b >= 30.0f);
        int nz2 = (int)(m & 1ull);
        int z3  = (int)((m >> (1 + nz2)) & 1ull);
        int nz4 = (int)((m >> (3 + z3)) & 1ull);
        int nz5 = (int)((m >> (5 + z3)) & 1ull);
        unsigned long long ssel =
            (nz2 ? 0x006ull : 0ull) | (z3 ? 0x078ull : 0ull)
          | (nz5 ? 0x180ull : 0ull);
        float Ia = sel_mask(V0, V1, ssel);
        float t7a = t6 + Ia;
        float dva = 0.25f * t7a;
        float v1a = v + dva;
        bool fa = (v1a >= 30.0f);
        v = fa ? c : v1a;
        float u1d = u1 + d;
        u = fa ? u1d : u1;
        psp[0] = fa ? 1.0f : 0.0f;
        pvv[0] = v;
        ++psp; ++pvv;
        z2 = nz2; z4 = nz4; z5 = nz5;
    }

    // publish detection result (ws is re-poisoned before every call)
    if (lane == 0) {
        ws[0] = (t_det >= 0) ? 1 : 0;
        ws[1] = t_det;
        ws[2] = Pf;
    }
}

// Fills out[r, t] for t in [t_det, T) with the periodic continuation
// out[r, t_det - P + ((t - t_det) mod P)]. No-op when no cycle was found.
__global__ __launch_bounds__(256) void fill_cycle(float* __restrict__ out,
                                                  const int* __restrict__ ws,
                                                  int T) {
    if (ws[0] == 0) return;
    const int t0 = ws[1];
    const int P  = ws[2];
    const int r  = blockIdx.y;                    // 0..9 (row)
    const float* __restrict__ src = out + (size_t)r * T + (t0 - P);
    float* __restrict__ dst       = out + (size_t)r * T + t0;
    const int n = T - t0;
    for (int i = blockIdx.x * blockDim.x + threadIdx.x; i < n;
         i += gridDim.x * blockDim.x) {
        dst[i] = src[i % P];
    }
}

extern "C" void kernel_launch(void* const* d_in, const int* in_sizes, int n_in,
                              void* d_out, int out_size, void* d_ws, size_t ws_size,
                              hipStream_t stream) {
    const float* mat = (const float*)d_in[0];
    const float* w   = (const float*)d_in[1];
    // out_size = 2 outputs * 5 neurons * T  -> T = out_size/10
    int T = out_size / 10;
    net_sim<<<1, 256, 0, stream>>>(mat, w, (float*)d_out, (int*)d_ws, T);
    dim3 grid(40, 10, 1);
    fill_cycle<<<grid, 256, 0, stream>>>((float*)d_out, (const int*)d_ws, T);
}